// Round 2
// baseline (1535.288 us; speedup 1.0000x reference)
//
#include <hip/hip_runtime.h>
#include <hip/hip_bf16.h>

// Self-attention (SAGAN-style) B=4, C=512, N=4096 (64x64), D=64.
// FLOAT32 in/out (per the reference's dtypes).
// out0 = gamma * (V @ A^T) + x   [B,C,64,64]  f32
// out1 = A = softmax(Q K)        [B,N,N]      f32
// Pipeline:
//   prep_weights: WqT/WkT [C][D] f32 (uniform s_load rows), Wvb bf16
//   transpose_cast: x f32 [C][N] -> xTb bf16 [N][C]   (for V MFMA B-operand)
//   proj_qk: f32 VALU, Q[n][d] & K[d][n]  (f32 keeps logits accurate)
//     round 2: d-split x4 -> 512 blocks (was 128: half the GPU idle), acc 16
//   proj_v:  bf16 MFMA, V[c][n] bf16 ws
//     round 2: cloned pv_out_fast 128x128 LDS-staged structure (was 1-wave
//     blocks with per-fragment global loads = latency-bound)
//   attn_softmax: f32 energy+softmax; writes f32 A to d_out + bf16 copy to ws
//     round 2: re-tiled 16 rows/1024 thr, acc[16][4]=64 regs (was 128 ->
//     2 waves/SIMD cap, VALUBusy 47%), dwordx4 K loads + manual prefetch
//   pv_out_fast: m97-style LDS-staged 128x128 bf16 MFMA GEMM + residual epi.

#define B_ 4
#define C_ 512
#define D_ 64
#define N_ 4096

typedef __hip_bfloat16 bf16;
typedef __attribute__((ext_vector_type(8))) short bf16x8;   // 8 bf16 = 4 VGPRs
typedef __attribute__((ext_vector_type(4))) float f32x4;

// async global->LDS, 16 bytes per lane. lds ptr must be wave-uniform base;
// HW writes base + lane*16. Global src is per-lane.
__device__ __forceinline__ void gload16(const void* g, void* l) {
    __builtin_amdgcn_global_load_lds(
        (__attribute__((address_space(1))) void*)g,
        (__attribute__((address_space(3))) void*)l, 16, 0, 0);
}

// ------------------------------------------------------------ weight prep
__global__ __launch_bounds__(256) void prep_weights(
        const float* __restrict__ Wq, const float* __restrict__ Wk,
        const float* __restrict__ Wv,
        float* __restrict__ WqT, float* __restrict__ WkT,
        bf16* __restrict__ Wvb) {
    int i = blockIdx.x * 256 + threadIdx.x;
    if (i < 32768) {                 // WqT[c][d] = Wq[d][c]
        int d = i >> 9, c = i & 511;
        WqT[c * 64 + d] = Wq[i];
    } else if (i < 65536) {
        int j = i - 32768;
        int d = j >> 9, c = j & 511;
        WkT[c * 64 + d] = Wk[j];
    } else {
        int j = i - 65536;
        if (j < 262144) Wvb[j] = __float2bfloat16(Wv[j]);
    }
}

// ------------------------------------------------------- transpose + cast
__global__ __launch_bounds__(256) void transpose_cast(const float* __restrict__ x,
                                                      bf16* __restrict__ xT) {
    __shared__ bf16 tile[32][33];
    int b = blockIdx.z;
    int n0 = blockIdx.x * 32;
    int c0 = blockIdx.y * 32;
    int tx = threadIdx.x;   // 0..31
    int ty = threadIdx.y;   // 0..7
    const float* xb = x + (size_t)b * C_ * N_;
    bf16* xTb = xT + (size_t)b * N_ * C_;
#pragma unroll
    for (int k = 0; k < 32; k += 8)
        tile[ty + k][tx] = __float2bfloat16(xb[(size_t)(c0 + ty + k) * N_ + n0 + tx]);
    __syncthreads();
#pragma unroll
    for (int k = 0; k < 32; k += 8)
        xTb[(size_t)(n0 + ty + k) * C_ + c0 + tx] = tile[tx][ty + k];
}

// ------------------------------------------------------ Q/K f32 projection
// blockIdx.z in 0..7: bit2 -> 0=Q,1=K; low 2 bits -> 16-wide d-quarter.
// One thread per token, 16 outputs each. 512 blocks -> 2/CU, 8 waves/CU.
__global__ __launch_bounds__(256) void proj_qk(
        const float* __restrict__ x,
        const float* __restrict__ WqT, const float* __restrict__ WkT,
        const float* __restrict__ bq, const float* __restrict__ bk,
        float* __restrict__ Q, float* __restrict__ Km) {
    int b = blockIdx.y;
    int z = blockIdx.z;
    int which = z >> 2;
    int dh = (z & 3) * 16;
    int n = blockIdx.x * 256 + threadIdx.x;
    const float* WT = which ? WkT : WqT;
    const float* bias = which ? bk : bq;
    const float* xb = x + (size_t)b * C_ * N_;

    float acc[16];
#pragma unroll
    for (int d = 0; d < 16; d++) acc[d] = 0.f;

    for (int c = 0; c < 512; c++) {
        float xv = xb[(size_t)c * N_ + n];
        const float* wrow = WT + c * 64 + dh;   // uniform -> scalar loads
#pragma unroll
        for (int d = 0; d < 16; d += 4) {
            float4 w = *(const float4*)(wrow + d);
            acc[d + 0] += w.x * xv;
            acc[d + 1] += w.y * xv;
            acc[d + 2] += w.z * xv;
            acc[d + 3] += w.w * xv;
        }
    }

    if (which == 0) {
        float* q = Q + ((size_t)b * N_ + n) * 64 + dh;
#pragma unroll
        for (int d = 0; d < 16; d += 4) {
            float4 v;
            v.x = acc[d + 0] + bias[dh + d + 0];
            v.y = acc[d + 1] + bias[dh + d + 1];
            v.z = acc[d + 2] + bias[dh + d + 2];
            v.w = acc[d + 3] + bias[dh + d + 3];
            *(float4*)(q + d) = v;
        }
    } else {
        float* kb = Km + (size_t)b * 64 * N_;
#pragma unroll
        for (int d = 0; d < 16; d++)
            kb[(size_t)(dh + d) * N_ + n] = acc[d] + bias[dh + d];
    }
}

// --------------------------------------------------------- V bf16 MFMA GEMM
// V[c][n] = sum_k Wvb[c][k] * xTb[n][k] + bv[c].
// Round 2: 128x128 tile, 4 waves, global_load_lds staging (pv_out_fast clone).
__global__ __launch_bounds__(256, 2) void proj_v(
        const bf16* __restrict__ Wvb, const bf16* __restrict__ xTb,
        const float* __restrict__ bv, bf16* __restrict__ V) {
    int b = blockIdx.z;
    int r0 = blockIdx.y * 128;     // cout rows
    int n0 = blockIdx.x * 128;     // token cols
    int tid = threadIdx.x;
    int wv = tid >> 6;
    int lane = tid & 63;
    int l15 = lane & 15;
    int kq  = lane >> 4;
    int wr = wv >> 1;
    int wc = wv & 1;

    __shared__ bf16 Ws[128 * 32];  // Wv tile [row][k]
    __shared__ bf16 Xs[128 * 32];  // xT tile [row][k]

    const bf16* Bb = xTb + (size_t)b * N_ * C_;

    int srow = tid >> 2;
    int scol = (tid & 3) * 8;
    bf16* WsW0 = Ws + wv * 512;
    bf16* XsW0 = Xs + wv * 512;

    f32x4 acc[4][4];
#pragma unroll
    for (int i = 0; i < 4; i++)
#pragma unroll
        for (int j = 0; j < 4; j++)
#pragma unroll
            for (int r = 0; r < 4; r++) acc[i][j][r] = 0.f;

    for (int kt = 0; kt < C_; kt += 32) {
#pragma unroll
        for (int rnd = 0; rnd < 2; rnd++) {
            int row = srow + rnd * 64;
            gload16(Wvb + (size_t)(r0 + row) * C_ + kt + scol, WsW0 + rnd * 2048);
            gload16(Bb + (size_t)(n0 + row) * C_ + kt + scol, XsW0 + rnd * 2048);
        }
        __syncthreads();

        bf16x8 af[4], bfr[4];
#pragma unroll
        for (int i = 0; i < 4; i++)
            af[i] = *(const bf16x8*)(Ws + (wr * 64 + i * 16 + l15) * 32 + kq * 8);
#pragma unroll
        for (int j = 0; j < 4; j++)
            bfr[j] = *(const bf16x8*)(Xs + (wc * 64 + j * 16 + l15) * 32 + kq * 8);
#pragma unroll
        for (int i = 0; i < 4; i++)
#pragma unroll
            for (int j = 0; j < 4; j++)
                acc[i][j] = __builtin_amdgcn_mfma_f32_16x16x32_bf16(af[i], bfr[j], acc[i][j], 0, 0, 0);
        __syncthreads();
    }

    bf16* Vb = V + (size_t)b * C_ * N_;
#pragma unroll
    for (int i = 0; i < 4; i++)
#pragma unroll
        for (int r = 0; r < 4; r++) {
            int row = r0 + wr * 64 + i * 16 + kq * 4 + r;
            float bvv = bv[row];
#pragma unroll
            for (int j = 0; j < 4; j++) {
                int col = n0 + wc * 64 + j * 16 + l15;
                Vb[(size_t)row * N_ + col] = __float2bfloat16(acc[i][j][r] + bvv);
            }
        }
}

// ------------------------------------------------- energy + fused softmax
// Round 2 re-tile: 16 rows/block, 1024 threads (16 waves). Thread t owns
// 4 consecutive cols (t*4..t*4+3): acc[16][4] = 64 VGPR (4 waves/SIMD vs 2),
// one global_load_dwordx4 of K per d (16B/lane), manual next-d prefetch.
// Q broadcast from LDS (wave-uniform -> no bank conflicts).
__global__ __launch_bounds__(1024, 4) void attn_softmax(
        const float* __restrict__ Q, const float* __restrict__ Km,
        float* __restrict__ attF, bf16* __restrict__ attB) {
    int b = blockIdx.y;
    int n0 = blockIdx.x * 16;
    int tid = threadIdx.x;           // 0..1023
    int wv = tid >> 6;               // wave 0..15
    int lane = tid & 63;
    int col = tid * 4;               // 4 consecutive cols per thread

    __shared__ float Qs[64][16];     // [d][r]
    __shared__ float red[16][16];    // [r][wave]

    {   // stage Q rows: one value per thread
        int r = tid >> 6, d = tid & 63;
        Qs[d][r] = Q[((size_t)b * N_ + n0 + r) * 64 + d];
    }
    __syncthreads();

    float acc[16][4];
#pragma unroll
    for (int r = 0; r < 16; r++)
#pragma unroll
        for (int j = 0; j < 4; j++) acc[r][j] = 0.f;

    const float* kp = Km + (size_t)b * 64 * N_ + col;
    float4 ka = *(const float4*)kp;
    for (int d = 0; d < 64; d++) {
        float4 kn;
        if (d < 63) kn = *(const float4*)(kp + (size_t)(d + 1) * N_);
        const float4* qrow = (const float4*)(&Qs[d][0]);
        float4 q0 = qrow[0], q1 = qrow[1], q2 = qrow[2], q3 = qrow[3];
        float qv[16] = {q0.x, q0.y, q0.z, q0.w, q1.x, q1.y, q1.z, q1.w,
                        q2.x, q2.y, q2.z, q2.w, q3.x, q3.y, q3.z, q3.w};
#pragma unroll
        for (int r = 0; r < 16; r++) {
            acc[r][0] = fmaf(ka.x, qv[r], acc[r][0]);
            acc[r][1] = fmaf(ka.y, qv[r], acc[r][1]);
            acc[r][2] = fmaf(ka.z, qv[r], acc[r][2]);
            acc[r][3] = fmaf(ka.w, qv[r], acc[r][3]);
        }
        ka = kn;
    }

    // ---- row max across 4096 cols
    float mx[16];
#pragma unroll
    for (int r = 0; r < 16; r++) {
        float m = fmaxf(fmaxf(acc[r][0], acc[r][1]), fmaxf(acc[r][2], acc[r][3]));
#pragma unroll
        for (int off = 32; off; off >>= 1) m = fmaxf(m, __shfl_xor(m, off, 64));
        if (lane == 0) red[r][wv] = m;
    }
    __syncthreads();
#pragma unroll
    for (int r = 0; r < 16; r++) {
        const float4* rp = (const float4*)(&red[r][0]);
        float4 a = rp[0], c = rp[1], e = rp[2], g = rp[3];
        mx[r] = fmaxf(fmaxf(fmaxf(fmaxf(a.x, a.y), fmaxf(a.z, a.w)),
                            fmaxf(fmaxf(c.x, c.y), fmaxf(c.z, c.w))),
                      fmaxf(fmaxf(fmaxf(e.x, e.y), fmaxf(e.z, e.w)),
                            fmaxf(fmaxf(g.x, g.y), fmaxf(g.z, g.w))));
    }
    __syncthreads();   // red reused for sums

    // ---- exp + row sum
    float inv[16];
#pragma unroll
    for (int r = 0; r < 16; r++) {
        acc[r][0] = __expf(acc[r][0] - mx[r]);
        acc[r][1] = __expf(acc[r][1] - mx[r]);
        acc[r][2] = __expf(acc[r][2] - mx[r]);
        acc[r][3] = __expf(acc[r][3] - mx[r]);
        float s = (acc[r][0] + acc[r][1]) + (acc[r][2] + acc[r][3]);
#pragma unroll
        for (int off = 32; off; off >>= 1) s += __shfl_xor(s, off, 64);
        if (lane == 0) red[r][wv] = s;
    }
    __syncthreads();
#pragma unroll
    for (int r = 0; r < 16; r++) {
        const float4* rp = (const float4*)(&red[r][0]);
        float4 a = rp[0], c = rp[1], e = rp[2], g = rp[3];
        float s = ((a.x + a.y) + (a.z + a.w)) + ((c.x + c.y) + (c.z + c.w))
                + ((e.x + e.y) + (e.z + e.w)) + ((g.x + g.y) + (g.z + g.w));
        inv[r] = 1.f / s;
    }

    // ---- write A (f32 out) + bf16 copy
    float* af = attF + (size_t)b * N_ * N_;
    bf16* ab = attB ? attB + (size_t)b * N_ * N_ : (bf16*)0;
#pragma unroll
    for (int r = 0; r < 16; r++) {
        size_t idx = (size_t)(n0 + r) * N_ + col;
        float4 p;
        p.x = acc[r][0] * inv[r];
        p.y = acc[r][1] * inv[r];
        p.z = acc[r][2] * inv[r];
        p.w = acc[r][3] * inv[r];
        *(float4*)(af + idx) = p;
        if (ab) {
            bf16 pb[4] = {__float2bfloat16(p.x), __float2bfloat16(p.y),
                          __float2bfloat16(p.z), __float2bfloat16(p.w)};
            *(short4*)(ab + idx) = *(short4*)pb;
        }
    }
}

// --------------------------------------------- PV GEMM + residual epilogue
// O[c][m] = sum_n V[c][n] * A[m][n];  out = gamma*O + x (f32).
// m97 structure: 128x128 tile, BK=32, 4 waves (2c x 2m, 64x64 each),
// global_load_lds width=16 staging, single-buffer 2-barrier K-loop.
__global__ __launch_bounds__(256, 2) void pv_out_fast(
        const bf16* __restrict__ V, const bf16* __restrict__ attB,
        const float* __restrict__ x, const float* __restrict__ gamma,
        float* __restrict__ out) {
    int b = blockIdx.z;
    int c0 = blockIdx.y * 128;     // output rows (channels)
    int m0 = blockIdx.x * 128;     // output cols (tokens)
    int tid = threadIdx.x;
    int wv = tid >> 6;             // wave 0..3
    int lane = tid & 63;
    int l15 = lane & 15;
    int kq  = lane >> 4;
    int wr = wv >> 1;              // wave c-half (0/1)
    int wc = wv & 1;               // wave m-half (0/1)

    __shared__ bf16 Vs[128 * 32];  // [row c][k] linear, 8 KB
    __shared__ bf16 As[128 * 32];  // [row m][k] linear, 8 KB

    const bf16* Vb = V + (size_t)b * C_ * N_;
    const bf16* Ab = attB + (size_t)b * N_ * N_;

    int srow = tid >> 2;           // 0..63 (+64 in round 1)
    int scol = (tid & 3) * 8;
    bf16* VsW0 = Vs + wv * 512;
    bf16* AsW0 = As + wv * 512;

    f32x4 acc[4][4];
#pragma unroll
    for (int i = 0; i < 4; i++)
#pragma unroll
        for (int j = 0; j < 4; j++)
#pragma unroll
            for (int r = 0; r < 4; r++) acc[i][j][r] = 0.f;

    for (int kt = 0; kt < N_; kt += 32) {
#pragma unroll
        for (int rnd = 0; rnd < 2; rnd++) {
            int row = srow + rnd * 64;
            gload16(Vb + (size_t)(c0 + row) * N_ + kt + scol, VsW0 + rnd * 2048);
            gload16(Ab + (size_t)(m0 + row) * N_ + kt + scol, AsW0 + rnd * 2048);
        }
        __syncthreads();

        bf16x8 af[4], bfr[4];
#pragma unroll
        for (int i = 0; i < 4; i++)
            af[i] = *(const bf16x8*)(Vs + (wr * 64 + i * 16 + l15) * 32 + kq * 8);
#pragma unroll
        for (int j = 0; j < 4; j++)
            bfr[j] = *(const bf16x8*)(As + (wc * 64 + j * 16 + l15) * 32 + kq * 8);
#pragma unroll
        for (int i = 0; i < 4; i++)
#pragma unroll
            for (int j = 0; j < 4; j++)
                acc[i][j] = __builtin_amdgcn_mfma_f32_16x16x32_bf16(af[i], bfr[j], acc[i][j], 0, 0, 0);
        __syncthreads();
    }

    float g = gamma[0];
    const float* xb = x + (size_t)b * C_ * N_;
    float* ob = out + (size_t)b * C_ * N_;
#pragma unroll
    for (int i = 0; i < 4; i++)
#pragma unroll
        for (int j = 0; j < 4; j++)
#pragma unroll
            for (int r = 0; r < 4; r++) {
                int row = c0 + wr * 64 + i * 16 + kq * 4 + r;
                int col = m0 + wc * 64 + j * 16 + l15;
                size_t idx = (size_t)row * N_ + col;
                ob[idx] = g * acc[i][j][r] + xb[idx];
            }
}

// -------------------- fallback PV (f32 attention, no bf16 ws copy avail)
__global__ __launch_bounds__(256, 2) void pv_out(
        const bf16* __restrict__ V, const bf16* __restrict__ attB,
        const float* __restrict__ attF,
        const float* __restrict__ x, const float* __restrict__ gamma,
        float* __restrict__ out) {
    int b = blockIdx.z;
    int wave = threadIdx.x >> 6;
    int c0 = blockIdx.y * 128 + (wave >> 1) * 64;
    int m0 = blockIdx.x * 128 + (wave & 1) * 64;
    int lane = threadIdx.x & 63;
    int l15 = lane & 15;
    int kq  = lane >> 4;

    const bf16* Vb = V + (size_t)b * C_ * N_;
    const bf16* AbB = attB ? attB + (size_t)b * N_ * N_ : (const bf16*)0;
    const float* AbF = attF + (size_t)b * N_ * N_;

    f32x4 acc[4][4];
#pragma unroll
    for (int i = 0; i < 4; i++)
#pragma unroll
        for (int j = 0; j < 4; j++)
#pragma unroll
            for (int r = 0; r < 4; r++) acc[i][j][r] = 0.f;

    for (int n = 0; n < N_; n += 32) {
        bf16x8 af[4], bfr[4];
#pragma unroll
        for (int i = 0; i < 4; i++)
            af[i] = *(const bf16x8*)(Vb + (size_t)(c0 + i * 16 + l15) * N_ + n + kq * 8);
        if (AbB) {
#pragma unroll
            for (int j = 0; j < 4; j++)
                bfr[j] = *(const bf16x8*)(AbB + (size_t)(m0 + j * 16 + l15) * N_ + n + kq * 8);
        } else {
#pragma unroll
            for (int j = 0; j < 4; j++) {
                const float* ap = AbF + (size_t)(m0 + j * 16 + l15) * N_ + n + kq * 8;
                float4 u = *(const float4*)ap;
                float4 w = *(const float4*)(ap + 4);
                bf16x8 bb;
                bf16* pb = (bf16*)&bb;
                pb[0] = __float2bfloat16(u.x); pb[1] = __float2bfloat16(u.y);
                pb[2] = __float2bfloat16(u.z); pb[3] = __float2bfloat16(u.w);
                pb[4] = __float2bfloat16(w.x); pb[5] = __float2bfloat16(w.y);
                pb[6] = __float2bfloat16(w.z); pb[7] = __float2bfloat16(w.w);
                bfr[j] = bb;
            }
        }
#pragma unroll
        for (int i = 0; i < 4; i++)
#pragma unroll
            for (int j = 0; j < 4; j++)
                acc[i][j] = __builtin_amdgcn_mfma_f32_16x16x32_bf16(af[i], bfr[j], acc[i][j], 0, 0, 0);
    }

    float g = gamma[0];
    const float* xb = x + (size_t)b * C_ * N_;
    float* ob = out + (size_t)b * C_ * N_;
#pragma unroll
    for (int i = 0; i < 4; i++)
#pragma unroll
        for (int j = 0; j < 4; j++)
#pragma unroll
            for (int r = 0; r < 4; r++) {
                int row = c0 + i * 16 + kq * 4 + r;
                int col = m0 + j * 16 + l15;
                size_t idx = (size_t)row * N_ + col;
                ob[idx] = g * acc[i][j][r] + xb[idx];
            }
}

// ------------------------------------------------------------------ launch
extern "C" void kernel_launch(void* const* d_in, const int* in_sizes, int n_in,
                              void* d_out, int out_size, void* d_ws, size_t ws_size,
                              hipStream_t stream) {
    const float* x     = (const float*)d_in[0];
    const float* Wq    = (const float*)d_in[1];
    const float* bq    = (const float*)d_in[2];
    const float* Wk    = (const float*)d_in[3];
    const float* bk    = (const float*)d_in[4];
    const float* Wv    = (const float*)d_in[5];
    const float* bv    = (const float*)d_in[6];
    const float* gamma = (const float*)d_in[7];
    (void)in_sizes; (void)n_in; (void)out_size;

    float* out  = (float*)d_out;
    float* attF = out + (size_t)B_ * C_ * N_;   // second tuple element, f32

    char* ws = (char*)d_ws;
    // layout (bytes): all offsets 16B-aligned
    float* Q   = (float*)(ws + 0);                      //  4 MB [B][N][D]
    float* K   = (float*)(ws + 4194304);                //  4 MB [B][D][N]
    bf16*  V   = (bf16*) (ws + 8388608);                // 16 MB [B][C][N]
    bf16*  xTb = (bf16*) (ws + 25165824);               // 16 MB [B][N][C]
    float* WqT = (float*)(ws + 41943040);               // 128 KB [C][D]
    float* WkT = (float*)(ws + 42074112);               // 128 KB [C][D]
    bf16*  Wvb = (bf16*) (ws + 42205184);               // 512 KB [C][C]
    bf16*  attB = (bf16*)(ws + 42729472);               // 128 MB [B][N][N]
    const size_t full_need = 42729472ULL + (size_t)B_ * N_ * N_ * 2;
    bf16* attB_use = (ws_size >= full_need) ? attB : (bf16*)0;

    prep_weights<<<1280, 256, 0, stream>>>(Wq, Wk, Wv, WqT, WkT, Wvb);

    transpose_cast<<<dim3(N_ / 32, C_ / 32, B_), dim3(32, 8), 0, stream>>>(x, xTb);

    proj_qk<<<dim3(N_ / 256, B_, 8), 256, 0, stream>>>(x, WqT, WkT, bq, bk, Q, K);

    proj_v<<<dim3(N_ / 128, C_ / 128, B_), 256, 0, stream>>>(Wvb, xTb, bv, V);

    attn_softmax<<<dim3(N_ / 16, B_), 1024, 0, stream>>>(Q, K, attF, attB_use);

    if (attB_use) {
        pv_out_fast<<<dim3(N_ / 128, C_ / 128, B_), 256, 0, stream>>>(
            V, attB_use, x, gamma, out);
    } else {
        pv_out<<<dim3(N_ / 128, C_ / 128, B_), 256, 0, stream>>>(
            V, attB_use, attF, x, gamma, out);
    }
}

// Round 3
// 842.057 us; speedup vs baseline: 1.8233x; 1.8233x over previous
//
#include <hip/hip_runtime.h>
#include <hip/hip_bf16.h>

// Self-attention (SAGAN-style) B=4, C=512, N=4096 (64x64), D=64.
// FLOAT32 in/out (per the reference's dtypes).
// out0 = gamma * (V @ A^T) + x   [B,C,64,64]  f32
// out1 = A = softmax(Q K)        [B,N,N]      f32
// Pipeline:
//   prep_weights: WqT/WkT [C][D] f32 (uniform s_load rows), Wvb bf16
//   transpose_cast: x f32 [C][N] -> xTb bf16 [N][C]   (for V MFMA B-operand)
//   proj_qk: f32 VALU; round 3: emits Qh/Ql/Kh/Kl token-major bf16 hi/lo
//     split (f32 Q/K dropped — MFMA energy with split is ~1e-4 accurate)
//   proj_v:  bf16 MFMA, 128x128 LDS-staged (round 2)
//   attn_fused: round 3 — MFMA energy (split-3) + online (m,s) pass +
//     recompute pass writing P. Swapped operands (K=A-op, Q=B-op) make the
//     row-reduction lane-local and stores float4-coalesced. Round-2 lesson:
//     1024-thr block + 64-reg cap spilled acc -> 2.1GB scratch writes; this
//     kernel keeps acc = one f32x4 (~60 VGPR, spill-proof).
//   pv_out_fast: m97-style LDS-staged 128x128 bf16 MFMA GEMM + residual epi.

#define B_ 4
#define C_ 512
#define D_ 64
#define N_ 4096

typedef __hip_bfloat16 bf16;
typedef __attribute__((ext_vector_type(8))) short bf16x8;   // 8 bf16 = 4 VGPRs
typedef __attribute__((ext_vector_type(4))) float f32x4;

// async global->LDS, 16 bytes per lane. lds ptr must be wave-uniform base;
// HW writes base + lane*16. Global src is per-lane.
__device__ __forceinline__ void gload16(const void* g, void* l) {
    __builtin_amdgcn_global_load_lds(
        (__attribute__((address_space(1))) void*)g,
        (__attribute__((address_space(3))) void*)l, 16, 0, 0);
}

// ------------------------------------------------------------ weight prep
__global__ __launch_bounds__(256) void prep_weights(
        const float* __restrict__ Wq, const float* __restrict__ Wk,
        const float* __restrict__ Wv,
        float* __restrict__ WqT, float* __restrict__ WkT,
        bf16* __restrict__ Wvb) {
    int i = blockIdx.x * 256 + threadIdx.x;
    if (i < 32768) {                 // WqT[c][d] = Wq[d][c]
        int d = i >> 9, c = i & 511;
        WqT[c * 64 + d] = Wq[i];
    } else if (i < 65536) {
        int j = i - 32768;
        int d = j >> 9, c = j & 511;
        WkT[c * 64 + d] = Wk[j];
    } else {
        int j = i - 65536;
        if (j < 262144) Wvb[j] = __float2bfloat16(Wv[j]);
    }
}

// ------------------------------------------------------- transpose + cast
__global__ __launch_bounds__(256) void transpose_cast(const float* __restrict__ x,
                                                      bf16* __restrict__ xT) {
    __shared__ bf16 tile[32][33];
    int b = blockIdx.z;
    int n0 = blockIdx.x * 32;
    int c0 = blockIdx.y * 32;
    int tx = threadIdx.x;   // 0..31
    int ty = threadIdx.y;   // 0..7
    const float* xb = x + (size_t)b * C_ * N_;
    bf16* xTb = xT + (size_t)b * N_ * C_;
#pragma unroll
    for (int k = 0; k < 32; k += 8)
        tile[ty + k][tx] = __float2bfloat16(xb[(size_t)(c0 + ty + k) * N_ + n0 + tx]);
    __syncthreads();
#pragma unroll
    for (int k = 0; k < 32; k += 8)
        xTb[(size_t)(n0 + ty + k) * C_ + c0 + tx] = tile[tx][ty + k];
}

// ------------------------------------------------------ Q/K f32 projection
// blockIdx.z in 0..7: bit2 -> 0=Q,1=K; low 2 bits -> 16-wide d-quarter.
// Round 3: outputs token-major bf16 hi/lo split pairs for MFMA energy.
__global__ __launch_bounds__(256) void proj_qk(
        const float* __restrict__ x,
        const float* __restrict__ WqT, const float* __restrict__ WkT,
        const float* __restrict__ bq, const float* __restrict__ bk,
        bf16* __restrict__ Qh, bf16* __restrict__ Ql,
        bf16* __restrict__ Kh, bf16* __restrict__ Kl) {
    int b = blockIdx.y;
    int z = blockIdx.z;
    int which = z >> 2;
    int dh = (z & 3) * 16;
    int n = blockIdx.x * 256 + threadIdx.x;
    const float* WT = which ? WkT : WqT;
    const float* bias = which ? bk : bq;
    bf16* Hd = (which ? Kh : Qh) + ((size_t)b * N_ + n) * 64 + dh;
    bf16* Ld = (which ? Kl : Ql) + ((size_t)b * N_ + n) * 64 + dh;
    const float* xb = x + (size_t)b * C_ * N_;

    float acc[16];
#pragma unroll
    for (int d = 0; d < 16; d++) acc[d] = 0.f;

    for (int c = 0; c < 512; c++) {
        float xv = xb[(size_t)c * N_ + n];
        const float* wrow = WT + c * 64 + dh;   // uniform -> scalar loads
#pragma unroll
        for (int d = 0; d < 16; d += 4) {
            float4 w = *(const float4*)(wrow + d);
            acc[d + 0] += w.x * xv;
            acc[d + 1] += w.y * xv;
            acc[d + 2] += w.z * xv;
            acc[d + 3] += w.w * xv;
        }
    }

    bf16x8 h0, h1, l0, l1;
    bf16* hp0 = (bf16*)&h0;
    bf16* hp1 = (bf16*)&h1;
    bf16* lp0 = (bf16*)&l0;
    bf16* lp1 = (bf16*)&l1;
#pragma unroll
    for (int d = 0; d < 8; d++) {
        float v = acc[d] + bias[dh + d];
        bf16 h = __float2bfloat16(v);
        hp0[d] = h;
        lp0[d] = __float2bfloat16(v - __bfloat162float(h));
    }
#pragma unroll
    for (int d = 8; d < 16; d++) {
        float v = acc[d] + bias[dh + d];
        bf16 h = __float2bfloat16(v);
        hp1[d - 8] = h;
        lp1[d - 8] = __float2bfloat16(v - __bfloat162float(h));
    }
    *(bf16x8*)(Hd)     = h0;
    *(bf16x8*)(Hd + 8) = h1;
    *(bf16x8*)(Ld)     = l0;
    *(bf16x8*)(Ld + 8) = l1;
}

// --------------------------------------------------------- V bf16 MFMA GEMM
// V[c][n] = sum_k Wvb[c][k] * xTb[n][k] + bv[c].
// Round 2: 128x128 tile, 4 waves, global_load_lds staging (pv_out_fast clone).
__global__ __launch_bounds__(256, 2) void proj_v(
        const bf16* __restrict__ Wvb, const bf16* __restrict__ xTb,
        const float* __restrict__ bv, bf16* __restrict__ V) {
    int b = blockIdx.z;
    int r0 = blockIdx.y * 128;     // cout rows
    int n0 = blockIdx.x * 128;     // token cols
    int tid = threadIdx.x;
    int wv = tid >> 6;
    int lane = tid & 63;
    int l15 = lane & 15;
    int kq  = lane >> 4;
    int wr = wv >> 1;
    int wc = wv & 1;

    __shared__ bf16 Ws[128 * 32];  // Wv tile [row][k]
    __shared__ bf16 Xs[128 * 32];  // xT tile [row][k]

    const bf16* Bb = xTb + (size_t)b * N_ * C_;

    int srow = tid >> 2;
    int scol = (tid & 3) * 8;
    bf16* WsW0 = Ws + wv * 512;
    bf16* XsW0 = Xs + wv * 512;

    f32x4 acc[4][4];
#pragma unroll
    for (int i = 0; i < 4; i++)
#pragma unroll
        for (int j = 0; j < 4; j++)
#pragma unroll
            for (int r = 0; r < 4; r++) acc[i][j][r] = 0.f;

    for (int kt = 0; kt < C_; kt += 32) {
#pragma unroll
        for (int rnd = 0; rnd < 2; rnd++) {
            int row = srow + rnd * 64;
            gload16(Wvb + (size_t)(r0 + row) * C_ + kt + scol, WsW0 + rnd * 2048);
            gload16(Bb + (size_t)(n0 + row) * C_ + kt + scol, XsW0 + rnd * 2048);
        }
        __syncthreads();

        bf16x8 af[4], bfr[4];
#pragma unroll
        for (int i = 0; i < 4; i++)
            af[i] = *(const bf16x8*)(Ws + (wr * 64 + i * 16 + l15) * 32 + kq * 8);
#pragma unroll
        for (int j = 0; j < 4; j++)
            bfr[j] = *(const bf16x8*)(Xs + (wc * 64 + j * 16 + l15) * 32 + kq * 8);
#pragma unroll
        for (int i = 0; i < 4; i++)
#pragma unroll
            for (int j = 0; j < 4; j++)
                acc[i][j] = __builtin_amdgcn_mfma_f32_16x16x32_bf16(af[i], bfr[j], acc[i][j], 0, 0, 0);
        __syncthreads();
    }

    bf16* Vb = V + (size_t)b * C_ * N_;
#pragma unroll
    for (int i = 0; i < 4; i++)
#pragma unroll
        for (int r = 0; r < 4; r++) {
            int row = r0 + wr * 64 + i * 16 + kq * 4 + r;
            float bvv = bv[row];
#pragma unroll
            for (int j = 0; j < 4; j++) {
                int col = n0 + wc * 64 + j * 16 + l15;
                Vb[(size_t)row * N_ + col] = __float2bfloat16(acc[i][j][r] + bvv);
            }
        }
}

// ------------------------------------------- fused MFMA energy + softmax
// Round 3. Block: 256 thr / 4 waves / 16 Q-rows; wave w owns cols w*1024.
// energy = Kh.Qh + Kh.Ql + Kl.Qh (bf16 hi/lo split, f32 acc; err ~1e-4).
// Swapped operands: K is the MFMA A-operand, Q the B-operand, so
// C/D row = K-col (kq*4+r, lane-local 4 consecutive cols), col = Q-row
// (l15). Phase 1: online per-row (m,s), no shuffles inside the j-loop.
// Phase 2: recompute energy, write P=exp(e-m)/s as f32 (+ bf16 copy).
__global__ __launch_bounds__(256, 4) void attn_fused(
        const bf16* __restrict__ Qh, const bf16* __restrict__ Ql,
        const bf16* __restrict__ Kh, const bf16* __restrict__ Kl,
        float* __restrict__ attF, bf16* __restrict__ attB) {
    int b = blockIdx.y;
    int n0 = blockIdx.x * 16;          // Q-row block
    int tid = threadIdx.x;
    int wv = tid >> 6;                 // wave: col range wv*1024
    int lane = tid & 63;
    int l15 = lane & 15;
    int kq = lane >> 4;

    const bf16* qhb = Qh + (size_t)b * N_ * 64;
    const bf16* qlb = Ql + (size_t)b * N_ * 64;
    const bf16* khb = Kh + (size_t)b * N_ * 64;
    const bf16* klb = Kl + (size_t)b * N_ * 64;

    // Q fragments (B-operand), fixed for the whole kernel: row n0+l15.
    const bf16* qrh = qhb + (size_t)(n0 + l15) * 64 + kq * 8;
    const bf16* qrl = qlb + (size_t)(n0 + l15) * 64 + kq * 8;
    bf16x8 bh0 = *(const bf16x8*)(qrh);
    bf16x8 bh1 = *(const bf16x8*)(qrh + 32);
    bf16x8 bl0 = *(const bf16x8*)(qrl);
    bf16x8 bl1 = *(const bf16x8*)(qrl + 32);

    // K fragment bases for this wave (advance 1024 elems per 16-col tile)
    const bf16* kwh = khb + (size_t)(wv * 1024 + l15) * 64 + kq * 8;
    const bf16* kwl = klb + (size_t)(wv * 1024 + l15) * 64 + kq * 8;

    float m = -3.0e38f, sl = 0.f;

    // ---------------- phase 1: online (m, s) over this wave's 1024 cols
    for (int j = 0; j < 64; j++) {
        const bf16* ph = kwh + (size_t)j * 1024;
        const bf16* pl = kwl + (size_t)j * 1024;
        bf16x8 a0 = *(const bf16x8*)(ph);
        bf16x8 a1 = *(const bf16x8*)(ph + 32);
        bf16x8 a2 = *(const bf16x8*)(pl);
        bf16x8 a3 = *(const bf16x8*)(pl + 32);
        f32x4 acc = {0.f, 0.f, 0.f, 0.f};
        acc = __builtin_amdgcn_mfma_f32_16x16x32_bf16(a0, bh0, acc, 0, 0, 0);
        acc = __builtin_amdgcn_mfma_f32_16x16x32_bf16(a1, bh1, acc, 0, 0, 0);
        acc = __builtin_amdgcn_mfma_f32_16x16x32_bf16(a0, bl0, acc, 0, 0, 0);
        acc = __builtin_amdgcn_mfma_f32_16x16x32_bf16(a1, bl1, acc, 0, 0, 0);
        acc = __builtin_amdgcn_mfma_f32_16x16x32_bf16(a2, bh0, acc, 0, 0, 0);
        acc = __builtin_amdgcn_mfma_f32_16x16x32_bf16(a3, bh1, acc, 0, 0, 0);
        float tm = fmaxf(fmaxf(acc[0], acc[1]), fmaxf(acc[2], acc[3]));
        float mn = fmaxf(m, tm);
        sl = sl * __expf(m - mn)
           + __expf(acc[0] - mn) + __expf(acc[1] - mn)
           + __expf(acc[2] - mn) + __expf(acc[3] - mn);
        m = mn;
    }

    // merge across the 4 kq-groups (same row, different col subsets)
#pragma unroll
    for (int mask = 16; mask <= 32; mask <<= 1) {
        float om = __shfl_xor(m, mask, 64);
        float os = __shfl_xor(sl, mask, 64);
        float mn = fmaxf(m, om);
        sl = sl * __expf(m - mn) + os * __expf(om - mn);
        m = mn;
    }

    // merge across the 4 waves (same rows, disjoint col ranges)
    __shared__ float redM[16][4];
    __shared__ float redS[16][4];
    if (lane < 16) { redM[l15][wv] = m; redS[l15][wv] = sl; }
    __syncthreads();
    float m0r = redM[l15][0], m1r = redM[l15][1];
    float m2r = redM[l15][2], m3r = redM[l15][3];
    float mf = fmaxf(fmaxf(m0r, m1r), fmaxf(m2r, m3r));
    float sf = redS[l15][0] * __expf(m0r - mf) + redS[l15][1] * __expf(m1r - mf)
             + redS[l15][2] * __expf(m2r - mf) + redS[l15][3] * __expf(m3r - mf);
    float inv = 1.f / sf;

    // ---------------- phase 2: recompute energy, write P
    float* af = attF + (size_t)b * N_ * N_ + (size_t)(n0 + l15) * N_
              + wv * 1024 + kq * 4;
    bf16* ab = attB ? attB + (size_t)b * N_ * N_ + (size_t)(n0 + l15) * N_
                       + wv * 1024 + kq * 4
                    : (bf16*)0;
    for (int j = 0; j < 64; j++) {
        const bf16* ph = kwh + (size_t)j * 1024;
        const bf16* pl = kwl + (size_t)j * 1024;
        bf16x8 a0 = *(const bf16x8*)(ph);
        bf16x8 a1 = *(const bf16x8*)(ph + 32);
        bf16x8 a2 = *(const bf16x8*)(pl);
        bf16x8 a3 = *(const bf16x8*)(pl + 32);
        f32x4 acc = {0.f, 0.f, 0.f, 0.f};
        acc = __builtin_amdgcn_mfma_f32_16x16x32_bf16(a0, bh0, acc, 0, 0, 0);
        acc = __builtin_amdgcn_mfma_f32_16x16x32_bf16(a1, bh1, acc, 0, 0, 0);
        acc = __builtin_amdgcn_mfma_f32_16x16x32_bf16(a0, bl0, acc, 0, 0, 0);
        acc = __builtin_amdgcn_mfma_f32_16x16x32_bf16(a1, bl1, acc, 0, 0, 0);
        acc = __builtin_amdgcn_mfma_f32_16x16x32_bf16(a2, bh0, acc, 0, 0, 0);
        acc = __builtin_amdgcn_mfma_f32_16x16x32_bf16(a3, bh1, acc, 0, 0, 0);
        float4 p;
        p.x = __expf(acc[0] - mf) * inv;
        p.y = __expf(acc[1] - mf) * inv;
        p.z = __expf(acc[2] - mf) * inv;
        p.w = __expf(acc[3] - mf) * inv;
        *(float4*)(af + j * 16) = p;
        if (ab) {
            bf16 pb[4] = {__float2bfloat16(p.x), __float2bfloat16(p.y),
                          __float2bfloat16(p.z), __float2bfloat16(p.w)};
            *(short4*)(ab + j * 16) = *(short4*)pb;
        }
    }
}

// --------------------------------------------- PV GEMM + residual epilogue
// O[c][m] = sum_n V[c][n] * A[m][n];  out = gamma*O + x (f32).
// m97 structure: 128x128 tile, BK=32, 4 waves (2c x 2m, 64x64 each),
// global_load_lds width=16 staging, single-buffer 2-barrier K-loop.
__global__ __launch_bounds__(256, 2) void pv_out_fast(
        const bf16* __restrict__ V, const bf16* __restrict__ attB,
        const float* __restrict__ x, const float* __restrict__ gamma,
        float* __restrict__ out) {
    int b = blockIdx.z;
    int c0 = blockIdx.y * 128;     // output rows (channels)
    int m0 = blockIdx.x * 128;     // output cols (tokens)
    int tid = threadIdx.x;
    int wv = tid >> 6;             // wave 0..3
    int lane = tid & 63;
    int l15 = lane & 15;
    int kq  = lane >> 4;
    int wr = wv >> 1;              // wave c-half (0/1)
    int wc = wv & 1;               // wave m-half (0/1)

    __shared__ bf16 Vs[128 * 32];  // [row c][k] linear, 8 KB
    __shared__ bf16 As[128 * 32];  // [row m][k] linear, 8 KB

    const bf16* Vb = V + (size_t)b * C_ * N_;
    const bf16* Ab = attB + (size_t)b * N_ * N_;

    int srow = tid >> 2;           // 0..63 (+64 in round 1)
    int scol = (tid & 3) * 8;
    bf16* VsW0 = Vs + wv * 512;
    bf16* AsW0 = As + wv * 512;

    f32x4 acc[4][4];
#pragma unroll
    for (int i = 0; i < 4; i++)
#pragma unroll
        for (int j = 0; j < 4; j++)
#pragma unroll
            for (int r = 0; r < 4; r++) acc[i][j][r] = 0.f;

    for (int kt = 0; kt < N_; kt += 32) {
#pragma unroll
        for (int rnd = 0; rnd < 2; rnd++) {
            int row = srow + rnd * 64;
            gload16(Vb + (size_t)(c0 + row) * N_ + kt + scol, VsW0 + rnd * 2048);
            gload16(Ab + (size_t)(m0 + row) * N_ + kt + scol, AsW0 + rnd * 2048);
        }
        __syncthreads();

        bf16x8 af[4], bfr[4];
#pragma unroll
        for (int i = 0; i < 4; i++)
            af[i] = *(const bf16x8*)(Vs + (wr * 64 + i * 16 + l15) * 32 + kq * 8);
#pragma unroll
        for (int j = 0; j < 4; j++)
            bfr[j] = *(const bf16x8*)(As + (wc * 64 + j * 16 + l15) * 32 + kq * 8);
#pragma unroll
        for (int i = 0; i < 4; i++)
#pragma unroll
            for (int j = 0; j < 4; j++)
                acc[i][j] = __builtin_amdgcn_mfma_f32_16x16x32_bf16(af[i], bfr[j], acc[i][j], 0, 0, 0);
        __syncthreads();
    }

    float g = gamma[0];
    const float* xb = x + (size_t)b * C_ * N_;
    float* ob = out + (size_t)b * C_ * N_;
#pragma unroll
    for (int i = 0; i < 4; i++)
#pragma unroll
        for (int j = 0; j < 4; j++)
#pragma unroll
            for (int r = 0; r < 4; r++) {
                int row = c0 + wr * 64 + i * 16 + kq * 4 + r;
                int col = m0 + wc * 64 + j * 16 + l15;
                size_t idx = (size_t)row * N_ + col;
                ob[idx] = g * acc[i][j][r] + xb[idx];
            }
}

// -------------------- fallback PV (f32 attention, no bf16 ws copy avail)
__global__ __launch_bounds__(256, 2) void pv_out(
        const bf16* __restrict__ V, const bf16* __restrict__ attB,
        const float* __restrict__ attF,
        const float* __restrict__ x, const float* __restrict__ gamma,
        float* __restrict__ out) {
    int b = blockIdx.z;
    int wave = threadIdx.x >> 6;
    int c0 = blockIdx.y * 128 + (wave >> 1) * 64;
    int m0 = blockIdx.x * 128 + (wave & 1) * 64;
    int lane = threadIdx.x & 63;
    int l15 = lane & 15;
    int kq  = lane >> 4;

    const bf16* Vb = V + (size_t)b * C_ * N_;
    const bf16* AbB = attB ? attB + (size_t)b * N_ * N_ : (const bf16*)0;
    const float* AbF = attF + (size_t)b * N_ * N_;

    f32x4 acc[4][4];
#pragma unroll
    for (int i = 0; i < 4; i++)
#pragma unroll
        for (int j = 0; j < 4; j++)
#pragma unroll
            for (int r = 0; r < 4; r++) acc[i][j][r] = 0.f;

    for (int n = 0; n < N_; n += 32) {
        bf16x8 af[4], bfr[4];
#pragma unroll
        for (int i = 0; i < 4; i++)
            af[i] = *(const bf16x8*)(Vb + (size_t)(c0 + i * 16 + l15) * N_ + n + kq * 8);
        if (AbB) {
#pragma unroll
            for (int j = 0; j < 4; j++)
                bfr[j] = *(const bf16x8*)(AbB + (size_t)(m0 + j * 16 + l15) * N_ + n + kq * 8);
        } else {
#pragma unroll
            for (int j = 0; j < 4; j++) {
                const float* ap = AbF + (size_t)(m0 + j * 16 + l15) * N_ + n + kq * 8;
                float4 u = *(const float4*)ap;
                float4 w = *(const float4*)(ap + 4);
                bf16x8 bb;
                bf16* pb = (bf16*)&bb;
                pb[0] = __float2bfloat16(u.x); pb[1] = __float2bfloat16(u.y);
                pb[2] = __float2bfloat16(u.z); pb[3] = __float2bfloat16(u.w);
                pb[4] = __float2bfloat16(w.x); pb[5] = __float2bfloat16(w.y);
                pb[6] = __float2bfloat16(w.z); pb[7] = __float2bfloat16(w.w);
                bfr[j] = bb;
            }
        }
#pragma unroll
        for (int i = 0; i < 4; i++)
#pragma unroll
            for (int j = 0; j < 4; j++)
                acc[i][j] = __builtin_amdgcn_mfma_f32_16x16x32_bf16(af[i], bfr[j], acc[i][j], 0, 0, 0);
    }

    float g = gamma[0];
    const float* xb = x + (size_t)b * C_ * N_;
    float* ob = out + (size_t)b * C_ * N_;
#pragma unroll
    for (int i = 0; i < 4; i++)
#pragma unroll
        for (int j = 0; j < 4; j++)
#pragma unroll
            for (int r = 0; r < 4; r++) {
                int row = c0 + i * 16 + kq * 4 + r;
                int col = m0 + j * 16 + l15;
                size_t idx = (size_t)row * N_ + col;
                ob[idx] = g * acc[i][j][r] + xb[idx];
            }
}

// ------------------------------------------------------------------ launch
extern "C" void kernel_launch(void* const* d_in, const int* in_sizes, int n_in,
                              void* d_out, int out_size, void* d_ws, size_t ws_size,
                              hipStream_t stream) {
    const float* x     = (const float*)d_in[0];
    const float* Wq    = (const float*)d_in[1];
    const float* bq    = (const float*)d_in[2];
    const float* Wk    = (const float*)d_in[3];
    const float* bk    = (const float*)d_in[4];
    const float* Wv    = (const float*)d_in[5];
    const float* bv    = (const float*)d_in[6];
    const float* gamma = (const float*)d_in[7];
    (void)in_sizes; (void)n_in; (void)out_size;

    float* out  = (float*)d_out;
    float* attF = out + (size_t)B_ * C_ * N_;   // second tuple element, f32

    char* ws = (char*)d_ws;
    // layout (bytes): all offsets 16B-aligned
    bf16*  qh  = (bf16*) (ws + 0);                      //  2 MB [B][N][64]
    bf16*  ql  = (bf16*) (ws + 2097152);                //  2 MB
    bf16*  kh  = (bf16*) (ws + 4194304);                //  2 MB
    bf16*  kl  = (bf16*) (ws + 6291456);                //  2 MB
    bf16*  V   = (bf16*) (ws + 8388608);                // 16 MB [B][C][N]
    bf16*  xTb = (bf16*) (ws + 25165824);               // 16 MB [B][N][C]
    float* WqT = (float*)(ws + 41943040);               // 128 KB [C][D]
    float* WkT = (float*)(ws + 42074112);               // 128 KB [C][D]
    bf16*  Wvb = (bf16*) (ws + 42205184);               // 512 KB [C][C]
    bf16*  attB = (bf16*)(ws + 42729472);               // 128 MB [B][N][N]
    const size_t full_need = 42729472ULL + (size_t)B_ * N_ * N_ * 2;
    bf16* attB_use = (ws_size >= full_need) ? attB : (bf16*)0;

    prep_weights<<<1280, 256, 0, stream>>>(Wq, Wk, Wv, WqT, WkT, Wvb);

    transpose_cast<<<dim3(N_ / 32, C_ / 32, B_), dim3(32, 8), 0, stream>>>(x, xTb);

    proj_qk<<<dim3(N_ / 256, B_, 8), 256, 0, stream>>>(x, WqT, WkT, bq, bk,
                                                       qh, ql, kh, kl);

    proj_v<<<dim3(N_ / 128, C_ / 128, B_), 256, 0, stream>>>(Wvb, xTb, bv, V);

    attn_fused<<<dim3(N_ / 16, B_), 256, 0, stream>>>(qh, ql, kh, kl,
                                                      attF, attB_use);

    if (attB_use) {
        pv_out_fast<<<dim3(N_ / 128, C_ / 128, B_), 256, 0, stream>>>(
            V, attB_use, x, gamma, out);
    } else {
        pv_out<<<dim3(N_ / 128, C_ / 128, B_), 256, 0, stream>>>(
            V, attB_use, attF, x, gamma, out);
    }
}

// Round 4
// 699.117 us; speedup vs baseline: 2.1960x; 1.2045x over previous
//
#include <hip/hip_runtime.h>
#include <hip/hip_bf16.h>

// Self-attention (SAGAN-style) B=4, C=512, N=4096 (64x64), D=64.
// FLOAT32 in/out (per the reference's dtypes).
// out0 = gamma * (V @ A^T) + x   [B,C,64,64]  f32
// out1 = A = softmax(Q K)        [B,N,N]      f32
// Pipeline:
//   prep_weights: WqT/WkT [C][D] f32 (uniform s_load rows), Wvb bf16
//   transpose_cast: x f32 [C][N] -> xTb bf16 [N][C]   (for V MFMA B-operand)
//   proj_qk: f32 VALU; emits Qh/Ql/Kh/Kl token-major bf16 hi/lo split
//   proj_v:  bf16 MFMA, 128x128 LDS-staged (round 2)
//   attn_fused: round 4 — same math as round 3 (swapped-operand MFMA energy,
//     split-3, two-pass online softmax) but rebuilt as an m97-style LDS-staged
//     engine. Round-3 counters: MfmaUtil 6.3%, VALUBusy 9%, VGPR 32 ->
//     latency/transaction-bound per-fragment global loads + operand remat.
//     Now: K tiles (64 tok x 64d, kh+kl) staged via global_load_lds with
//     XOR-swizzle (128B rows = G4's 16-way conflict case; pre-swizzled
//     global src + swizzled ds_read, rule 21), 4 independent MFMA chains,
//     Q frags pinned in regs via keep-alive asm.
//   pv_out_fast: m97-style LDS-staged 128x128 bf16 MFMA GEMM + residual epi.

#define B_ 4
#define C_ 512
#define D_ 64
#define N_ 4096

typedef __hip_bfloat16 bf16;
typedef __attribute__((ext_vector_type(8))) short bf16x8;   // 8 bf16 = 4 VGPRs
typedef __attribute__((ext_vector_type(4))) float f32x4;

// async global->LDS, 16 bytes per lane. lds ptr must be wave-uniform base;
// HW writes base + lane*16. Global src is per-lane.
__device__ __forceinline__ void gload16(const void* g, void* l) {
    __builtin_amdgcn_global_load_lds(
        (__attribute__((address_space(1))) void*)g,
        (__attribute__((address_space(3))) void*)l, 16, 0, 0);
}

// ------------------------------------------------------------ weight prep
__global__ __launch_bounds__(256) void prep_weights(
        const float* __restrict__ Wq, const float* __restrict__ Wk,
        const float* __restrict__ Wv,
        float* __restrict__ WqT, float* __restrict__ WkT,
        bf16* __restrict__ Wvb) {
    int i = blockIdx.x * 256 + threadIdx.x;
    if (i < 32768) {                 // WqT[c][d] = Wq[d][c]
        int d = i >> 9, c = i & 511;
        WqT[c * 64 + d] = Wq[i];
    } else if (i < 65536) {
        int j = i - 32768;
        int d = j >> 9, c = j & 511;
        WkT[c * 64 + d] = Wk[j];
    } else {
        int j = i - 65536;
        if (j < 262144) Wvb[j] = __float2bfloat16(Wv[j]);
    }
}

// ------------------------------------------------------- transpose + cast
__global__ __launch_bounds__(256) void transpose_cast(const float* __restrict__ x,
                                                      bf16* __restrict__ xT) {
    __shared__ bf16 tile[32][33];
    int b = blockIdx.z;
    int n0 = blockIdx.x * 32;
    int c0 = blockIdx.y * 32;
    int tx = threadIdx.x;   // 0..31
    int ty = threadIdx.y;   // 0..7
    const float* xb = x + (size_t)b * C_ * N_;
    bf16* xTb = xT + (size_t)b * N_ * C_;
#pragma unroll
    for (int k = 0; k < 32; k += 8)
        tile[ty + k][tx] = __float2bfloat16(xb[(size_t)(c0 + ty + k) * N_ + n0 + tx]);
    __syncthreads();
#pragma unroll
    for (int k = 0; k < 32; k += 8)
        xTb[(size_t)(n0 + ty + k) * C_ + c0 + tx] = tile[tx][ty + k];
}

// ------------------------------------------------------ Q/K f32 projection
// blockIdx.z in 0..7: bit2 -> 0=Q,1=K; low 2 bits -> 16-wide d-quarter.
// Outputs token-major bf16 hi/lo split pairs for MFMA energy.
__global__ __launch_bounds__(256) void proj_qk(
        const float* __restrict__ x,
        const float* __restrict__ WqT, const float* __restrict__ WkT,
        const float* __restrict__ bq, const float* __restrict__ bk,
        bf16* __restrict__ Qh, bf16* __restrict__ Ql,
        bf16* __restrict__ Kh, bf16* __restrict__ Kl) {
    int b = blockIdx.y;
    int z = blockIdx.z;
    int which = z >> 2;
    int dh = (z & 3) * 16;
    int n = blockIdx.x * 256 + threadIdx.x;
    const float* WT = which ? WkT : WqT;
    const float* bias = which ? bk : bq;
    bf16* Hd = (which ? Kh : Qh) + ((size_t)b * N_ + n) * 64 + dh;
    bf16* Ld = (which ? Kl : Ql) + ((size_t)b * N_ + n) * 64 + dh;
    const float* xb = x + (size_t)b * C_ * N_;

    float acc[16];
#pragma unroll
    for (int d = 0; d < 16; d++) acc[d] = 0.f;

    for (int c = 0; c < 512; c++) {
        float xv = xb[(size_t)c * N_ + n];
        const float* wrow = WT + c * 64 + dh;   // uniform -> scalar loads
#pragma unroll
        for (int d = 0; d < 16; d += 4) {
            float4 w = *(const float4*)(wrow + d);
            acc[d + 0] += w.x * xv;
            acc[d + 1] += w.y * xv;
            acc[d + 2] += w.z * xv;
            acc[d + 3] += w.w * xv;
        }
    }

    bf16x8 h0, h1, l0, l1;
    bf16* hp0 = (bf16*)&h0;
    bf16* hp1 = (bf16*)&h1;
    bf16* lp0 = (bf16*)&l0;
    bf16* lp1 = (bf16*)&l1;
#pragma unroll
    for (int d = 0; d < 8; d++) {
        float v = acc[d] + bias[dh + d];
        bf16 h = __float2bfloat16(v);
        hp0[d] = h;
        lp0[d] = __float2bfloat16(v - __bfloat162float(h));
    }
#pragma unroll
    for (int d = 8; d < 16; d++) {
        float v = acc[d] + bias[dh + d];
        bf16 h = __float2bfloat16(v);
        hp1[d - 8] = h;
        lp1[d - 8] = __float2bfloat16(v - __bfloat162float(h));
    }
    *(bf16x8*)(Hd)     = h0;
    *(bf16x8*)(Hd + 8) = h1;
    *(bf16x8*)(Ld)     = l0;
    *(bf16x8*)(Ld + 8) = l1;
}

// --------------------------------------------------------- V bf16 MFMA GEMM
// V[c][n] = sum_k Wvb[c][k] * xTb[n][k] + bv[c].
// 128x128 tile, 4 waves, global_load_lds staging (pv_out_fast clone).
__global__ __launch_bounds__(256, 2) void proj_v(
        const bf16* __restrict__ Wvb, const bf16* __restrict__ xTb,
        const float* __restrict__ bv, bf16* __restrict__ V) {
    int b = blockIdx.z;
    int r0 = blockIdx.y * 128;     // cout rows
    int n0 = blockIdx.x * 128;     // token cols
    int tid = threadIdx.x;
    int wv = tid >> 6;
    int lane = tid & 63;
    int l15 = lane & 15;
    int kq  = lane >> 4;
    int wr = wv >> 1;
    int wc = wv & 1;

    __shared__ bf16 Ws[128 * 32];  // Wv tile [row][k]
    __shared__ bf16 Xs[128 * 32];  // xT tile [row][k]

    const bf16* Bb = xTb + (size_t)b * N_ * C_;

    int srow = tid >> 2;
    int scol = (tid & 3) * 8;
    bf16* WsW0 = Ws + wv * 512;
    bf16* XsW0 = Xs + wv * 512;

    f32x4 acc[4][4];
#pragma unroll
    for (int i = 0; i < 4; i++)
#pragma unroll
        for (int j = 0; j < 4; j++)
#pragma unroll
            for (int r = 0; r < 4; r++) acc[i][j][r] = 0.f;

    for (int kt = 0; kt < C_; kt += 32) {
#pragma unroll
        for (int rnd = 0; rnd < 2; rnd++) {
            int row = srow + rnd * 64;
            gload16(Wvb + (size_t)(r0 + row) * C_ + kt + scol, WsW0 + rnd * 2048);
            gload16(Bb + (size_t)(n0 + row) * C_ + kt + scol, XsW0 + rnd * 2048);
        }
        __syncthreads();

        bf16x8 af[4], bfr[4];
#pragma unroll
        for (int i = 0; i < 4; i++)
            af[i] = *(const bf16x8*)(Ws + (wr * 64 + i * 16 + l15) * 32 + kq * 8);
#pragma unroll
        for (int j = 0; j < 4; j++)
            bfr[j] = *(const bf16x8*)(Xs + (wc * 64 + j * 16 + l15) * 32 + kq * 8);
#pragma unroll
        for (int i = 0; i < 4; i++)
#pragma unroll
            for (int j = 0; j < 4; j++)
                acc[i][j] = __builtin_amdgcn_mfma_f32_16x16x32_bf16(af[i], bfr[j], acc[i][j], 0, 0, 0);
        __syncthreads();
    }

    bf16* Vb = V + (size_t)b * C_ * N_;
#pragma unroll
    for (int i = 0; i < 4; i++)
#pragma unroll
        for (int r = 0; r < 4; r++) {
            int row = r0 + wr * 64 + i * 16 + kq * 4 + r;
            float bvv = bv[row];
#pragma unroll
            for (int j = 0; j < 4; j++) {
                int col = n0 + wc * 64 + j * 16 + l15;
                Vb[(size_t)row * N_ + col] = __float2bfloat16(acc[i][j][r] + bvv);
            }
        }
}

// ------------------------------------------- fused MFMA energy + softmax
// Round 4: LDS-staged GEMM engine. Block = 32 Q-rows x 4096 cols, 4 waves
// (wr = row-group 0/1 -> 16 rows each; wc = col-half 0/1 -> 2048 cols).
// Per col-half, K tiles of 64 tokens (kh + kl, [64][64] bf16 = 128B rows)
// staged by the two wr-waves via global_load_lds; XOR swizzle chunk^=(row&7)
// applied on the GLOBAL source (LDS dest is linear, rule 21) and on the
// ds_read address -> 2-way banks (free). energy = Kh.Qh + Kh.Ql + Kl.Qh.
// Pass 1: online (m,s), lane-local (lane = (qrow l15, colgroup kq)).
// Pass 2: recompute, write P f32 (+ bf16 copy).
__global__ __launch_bounds__(256, 4) void attn_fused(
        const bf16* __restrict__ Qh, const bf16* __restrict__ Ql,
        const bf16* __restrict__ Kh, const bf16* __restrict__ Kl,
        float* __restrict__ attF, bf16* __restrict__ attB) {
    int b = blockIdx.y;
    int n0 = blockIdx.x * 32;          // Q-row block
    int tid = threadIdx.x;
    int wv = tid >> 6;
    int wr = wv >> 1;                  // row-group (16 rows)
    int wc = wv & 1;                   // col-half (2048 cols)
    int lane = tid & 63;
    int l15 = lane & 15;
    int kq = lane >> 4;

    // LDS: per col-half, kh and kl tiles of [64 tokens][64 d] bf16 (8 KB each)
    __shared__ bf16 Ks[2][2][64 * 64];
    __shared__ float redM[32][2];
    __shared__ float redS[32][2];

    const bf16* qhb = Qh + (size_t)b * N_ * 64;
    const bf16* qlb = Ql + (size_t)b * N_ * 64;
    const bf16* khl = (wr ? Kl : Kh) + (size_t)b * N_ * 64;  // this wave stages

    // Q fragments (B-operand), fixed: row n0 + wr*16 + l15.
    int qrow = n0 + wr * 16 + l15;
    const bf16* qrh = qhb + (size_t)qrow * 64 + kq * 8;
    const bf16* qrl = qlb + (size_t)qrow * 64 + kq * 8;
    bf16x8 bh0 = *(const bf16x8*)(qrh);
    bf16x8 bh1 = *(const bf16x8*)(qrh + 32);
    bf16x8 bl0 = *(const bf16x8*)(qrl);
    bf16x8 bl1 = *(const bf16x8*)(qrl + 32);
    // pin in VGPRs (round-3 showed the compiler remats these as loads)
    asm volatile("" : "+v"(bh0), "+v"(bh1), "+v"(bl0), "+v"(bl1));

    // staging map (per wave, 8 rounds): lane l -> row l>>3, chunk (l&7)^(l>>3)
    // (LDS dest linear: round r -> bytes r*1024 + lane*16)
    int srow_ = lane >> 3;                       // 0..7 within round
    int schunk = (lane & 7) ^ srow_;             // pre-swizzled global chunk
    const bf16* ksrc = khl + (size_t)srow_ * 64 + schunk * 8;
    bf16* kdst = &Ks[wc][wr][0];

    // ds_read swizzled element offsets for the 4 frag classes (kk 0/1):
    // frag(token tr, kk): elems tr*64 + ((kk*4+kq)^(tr&7))*8
    int tr_base = l15;                            // + s*16
    int sw0 = ((kq) ^ (l15 & 7)) * 8;             // kk=0 chunk
    int sw1 = ((4 + kq) ^ (l15 & 7)) * 8;         // kk=1 chunk

    const bf16* khs = &Ks[wc][0][0];
    const bf16* kls = &Ks[wc][1][0];

    float m = -3.0e38f, sl = 0.f;

    // ---------------- pass 1: online (m, s) over this half's 2048 cols
    for (int t = 0; t < 32; t++) {
        int t0 = wc * 2048 + t * 64;
#pragma unroll
        for (int r = 0; r < 8; r++)
            gload16(ksrc + (size_t)(t0 + r * 8) * 64, kdst + r * 512);
        __syncthreads();

        f32x4 acc[4];
#pragma unroll
        for (int s = 0; s < 4; s++) {
            int tr = s * 16 + tr_base;
            const bf16* ph = khs + tr * 64;
            const bf16* pl = kls + tr * 64;
            bf16x8 a0 = *(const bf16x8*)(ph + sw0);
            bf16x8 a1 = *(const bf16x8*)(ph + sw1);
            bf16x8 a2 = *(const bf16x8*)(pl + sw0);
            bf16x8 a3 = *(const bf16x8*)(pl + sw1);
            f32x4 ac = {0.f, 0.f, 0.f, 0.f};
            ac = __builtin_amdgcn_mfma_f32_16x16x32_bf16(a0, bh0, ac, 0, 0, 0);
            ac = __builtin_amdgcn_mfma_f32_16x16x32_bf16(a1, bh1, ac, 0, 0, 0);
            ac = __builtin_amdgcn_mfma_f32_16x16x32_bf16(a0, bl0, ac, 0, 0, 0);
            ac = __builtin_amdgcn_mfma_f32_16x16x32_bf16(a1, bl1, ac, 0, 0, 0);
            ac = __builtin_amdgcn_mfma_f32_16x16x32_bf16(a2, bh0, ac, 0, 0, 0);
            ac = __builtin_amdgcn_mfma_f32_16x16x32_bf16(a3, bh1, ac, 0, 0, 0);
            acc[s] = ac;
        }
        __syncthreads();

        // one combined online update per tile (16 values)
        float tm = acc[0][0];
#pragma unroll
        for (int s = 0; s < 4; s++)
#pragma unroll
            for (int r = 0; r < 4; r++) tm = fmaxf(tm, acc[s][r]);
        float mn = fmaxf(m, tm);
        float ssum = 0.f;
#pragma unroll
        for (int s = 0; s < 4; s++)
#pragma unroll
            for (int r = 0; r < 4; r++) ssum += __expf(acc[s][r] - mn);
        sl = sl * __expf(m - mn) + ssum;
        m = mn;
    }

    // merge across the 4 kq-groups (same row, disjoint col subsets)
#pragma unroll
    for (int mask = 16; mask <= 32; mask <<= 1) {
        float om = __shfl_xor(m, mask, 64);
        float os = __shfl_xor(sl, mask, 64);
        float mn = fmaxf(m, om);
        sl = sl * __expf(m - mn) + os * __expf(om - mn);
        m = mn;
    }

    // merge across the 2 col-halves (waves with same wr)
    int row_local = wr * 16 + l15;
    if (lane < 16) { redM[row_local][wc] = m; redS[row_local][wc] = sl; }
    __syncthreads();
    float m0r = redM[row_local][0], m1r = redM[row_local][1];
    float mf = fmaxf(m0r, m1r);
    float sf = redS[row_local][0] * __expf(m0r - mf)
             + redS[row_local][1] * __expf(m1r - mf);
    float inv = 1.f / sf;

    // ---------------- pass 2: recompute energy, write P
    float* af = attF + (size_t)b * N_ * N_ + (size_t)qrow * N_ + wc * 2048 + kq * 4;
    bf16* ab = attB ? attB + (size_t)b * N_ * N_ + (size_t)qrow * N_ + wc * 2048 + kq * 4
                    : (bf16*)0;
    for (int t = 0; t < 32; t++) {
        int t0 = wc * 2048 + t * 64;
#pragma unroll
        for (int r = 0; r < 8; r++)
            gload16(ksrc + (size_t)(t0 + r * 8) * 64, kdst + r * 512);
        __syncthreads();

#pragma unroll
        for (int s = 0; s < 4; s++) {
            int tr = s * 16 + tr_base;
            const bf16* ph = khs + tr * 64;
            const bf16* pl = kls + tr * 64;
            bf16x8 a0 = *(const bf16x8*)(ph + sw0);
            bf16x8 a1 = *(const bf16x8*)(ph + sw1);
            bf16x8 a2 = *(const bf16x8*)(pl + sw0);
            bf16x8 a3 = *(const bf16x8*)(pl + sw1);
            f32x4 ac = {0.f, 0.f, 0.f, 0.f};
            ac = __builtin_amdgcn_mfma_f32_16x16x32_bf16(a0, bh0, ac, 0, 0, 0);
            ac = __builtin_amdgcn_mfma_f32_16x16x32_bf16(a1, bh1, ac, 0, 0, 0);
            ac = __builtin_amdgcn_mfma_f32_16x16x32_bf16(a0, bl0, ac, 0, 0, 0);
            ac = __builtin_amdgcn_mfma_f32_16x16x32_bf16(a1, bl1, ac, 0, 0, 0);
            ac = __builtin_amdgcn_mfma_f32_16x16x32_bf16(a2, bh0, ac, 0, 0, 0);
            ac = __builtin_amdgcn_mfma_f32_16x16x32_bf16(a3, bh1, ac, 0, 0, 0);
            float4 p;
            p.x = __expf(ac[0] - mf) * inv;
            p.y = __expf(ac[1] - mf) * inv;
            p.z = __expf(ac[2] - mf) * inv;
            p.w = __expf(ac[3] - mf) * inv;
            int coff = t * 64 + s * 16;
            *(float4*)(af + coff) = p;
            if (ab) {
                bf16 pb[4] = {__float2bfloat16(p.x), __float2bfloat16(p.y),
                              __float2bfloat16(p.z), __float2bfloat16(p.w)};
                *(short4*)(ab + coff) = *(short4*)pb;
            }
        }
        __syncthreads();
    }
}

// --------------------------------------------- PV GEMM + residual epilogue
// O[c][m] = sum_n V[c][n] * A[m][n];  out = gamma*O + x (f32).
// m97 structure: 128x128 tile, BK=32, 4 waves (2c x 2m, 64x64 each),
// global_load_lds width=16 staging, single-buffer 2-barrier K-loop.
__global__ __launch_bounds__(256, 2) void pv_out_fast(
        const bf16* __restrict__ V, const bf16* __restrict__ attB,
        const float* __restrict__ x, const float* __restrict__ gamma,
        float* __restrict__ out) {
    int b = blockIdx.z;
    int c0 = blockIdx.y * 128;     // output rows (channels)
    int m0 = blockIdx.x * 128;     // output cols (tokens)
    int tid = threadIdx.x;
    int wv = tid >> 6;             // wave 0..3
    int lane = tid & 63;
    int l15 = lane & 15;
    int kq  = lane >> 4;
    int wr = wv >> 1;              // wave c-half (0/1)
    int wc = wv & 1;               // wave m-half (0/1)

    __shared__ bf16 Vs[128 * 32];  // [row c][k] linear, 8 KB
    __shared__ bf16 As[128 * 32];  // [row m][k] linear, 8 KB

    const bf16* Vb = V + (size_t)b * C_ * N_;
    const bf16* Ab = attB + (size_t)b * N_ * N_;

    int srow = tid >> 2;
    int scol = (tid & 3) * 8;
    bf16* VsW0 = Vs + wv * 512;
    bf16* AsW0 = As + wv * 512;

    f32x4 acc[4][4];
#pragma unroll
    for (int i = 0; i < 4; i++)
#pragma unroll
        for (int j = 0; j < 4; j++)
#pragma unroll
            for (int r = 0; r < 4; r++) acc[i][j][r] = 0.f;

    for (int kt = 0; kt < N_; kt += 32) {
#pragma unroll
        for (int rnd = 0; rnd < 2; rnd++) {
            int row = srow + rnd * 64;
            gload16(Vb + (size_t)(c0 + row) * N_ + kt + scol, VsW0 + rnd * 2048);
            gload16(Ab + (size_t)(m0 + row) * N_ + kt + scol, AsW0 + rnd * 2048);
        }
        __syncthreads();

        bf16x8 af[4], bfr[4];
#pragma unroll
        for (int i = 0; i < 4; i++)
            af[i] = *(const bf16x8*)(Vs + (wr * 64 + i * 16 + l15) * 32 + kq * 8);
#pragma unroll
        for (int j = 0; j < 4; j++)
            bfr[j] = *(const bf16x8*)(As + (wc * 64 + j * 16 + l15) * 32 + kq * 8);
#pragma unroll
        for (int i = 0; i < 4; i++)
#pragma unroll
            for (int j = 0; j < 4; j++)
                acc[i][j] = __builtin_amdgcn_mfma_f32_16x16x32_bf16(af[i], bfr[j], acc[i][j], 0, 0, 0);
        __syncthreads();
    }

    float g = gamma[0];
    const float* xb = x + (size_t)b * C_ * N_;
    float* ob = out + (size_t)b * C_ * N_;
#pragma unroll
    for (int i = 0; i < 4; i++)
#pragma unroll
        for (int j = 0; j < 4; j++)
#pragma unroll
            for (int r = 0; r < 4; r++) {
                int row = c0 + wr * 64 + i * 16 + kq * 4 + r;
                int col = m0 + wc * 64 + j * 16 + l15;
                size_t idx = (size_t)row * N_ + col;
                ob[idx] = g * acc[i][j][r] + xb[idx];
            }
}

// -------------------- fallback PV (f32 attention, no bf16 ws copy avail)
__global__ __launch_bounds__(256, 2) void pv_out(
        const bf16* __restrict__ V, const bf16* __restrict__ attB,
        const float* __restrict__ attF,
        const float* __restrict__ x, const float* __restrict__ gamma,
        float* __restrict__ out) {
    int b = blockIdx.z;
    int wave = threadIdx.x >> 6;
    int c0 = blockIdx.y * 128 + (wave >> 1) * 64;
    int m0 = blockIdx.x * 128 + (wave & 1) * 64;
    int lane = threadIdx.x & 63;
    int l15 = lane & 15;
    int kq  = lane >> 4;

    const bf16* Vb = V + (size_t)b * C_ * N_;
    const bf16* AbB = attB ? attB + (size_t)b * N_ * N_ : (const bf16*)0;
    const float* AbF = attF + (size_t)b * N_ * N_;

    f32x4 acc[4][4];
#pragma unroll
    for (int i = 0; i < 4; i++)
#pragma unroll
        for (int j = 0; j < 4; j++)
#pragma unroll
            for (int r = 0; r < 4; r++) acc[i][j][r] = 0.f;

    for (int n = 0; n < N_; n += 32) {
        bf16x8 af[4], bfr[4];
#pragma unroll
        for (int i = 0; i < 4; i++)
            af[i] = *(const bf16x8*)(Vb + (size_t)(c0 + i * 16 + l15) * N_ + n + kq * 8);
        if (AbB) {
#pragma unroll
            for (int j = 0; j < 4; j++)
                bfr[j] = *(const bf16x8*)(AbB + (size_t)(m0 + j * 16 + l15) * N_ + n + kq * 8);
        } else {
#pragma unroll
            for (int j = 0; j < 4; j++) {
                const float* ap = AbF + (size_t)(m0 + j * 16 + l15) * N_ + n + kq * 8;
                float4 u = *(const float4*)ap;
                float4 w = *(const float4*)(ap + 4);
                bf16x8 bb;
                bf16* pb = (bf16*)&bb;
                pb[0] = __float2bfloat16(u.x); pb[1] = __float2bfloat16(u.y);
                pb[2] = __float2bfloat16(u.z); pb[3] = __float2bfloat16(u.w);
                pb[4] = __float2bfloat16(w.x); pb[5] = __float2bfloat16(w.y);
                pb[6] = __float2bfloat16(w.z); pb[7] = __float2bfloat16(w.w);
                bfr[j] = bb;
            }
        }
#pragma unroll
        for (int i = 0; i < 4; i++)
#pragma unroll
            for (int j = 0; j < 4; j++)
                acc[i][j] = __builtin_amdgcn_mfma_f32_16x16x32_bf16(af[i], bfr[j], acc[i][j], 0, 0, 0);
    }

    float g = gamma[0];
    const float* xb = x + (size_t)b * C_ * N_;
    float* ob = out + (size_t)b * C_ * N_;
#pragma unroll
    for (int i = 0; i < 4; i++)
#pragma unroll
        for (int j = 0; j < 4; j++)
#pragma unroll
            for (int r = 0; r < 4; r++) {
                int row = c0 + i * 16 + kq * 4 + r;
                int col = m0 + j * 16 + l15;
                size_t idx = (size_t)row * N_ + col;
                ob[idx] = g * acc[i][j][r] + xb[idx];
            }
}

// ------------------------------------------------------------------ launch
extern "C" void kernel_launch(void* const* d_in, const int* in_sizes, int n_in,
                              void* d_out, int out_size, void* d_ws, size_t ws_size,
                              hipStream_t stream) {
    const float* x     = (const float*)d_in[0];
    const float* Wq    = (const float*)d_in[1];
    const float* bq    = (const float*)d_in[2];
    const float* Wk    = (const float*)d_in[3];
    const float* bk    = (const float*)d_in[4];
    const float* Wv    = (const float*)d_in[5];
    const float* bv    = (const float*)d_in[6];
    const float* gamma = (const float*)d_in[7];
    (void)in_sizes; (void)n_in; (void)out_size;

    float* out  = (float*)d_out;
    float* attF = out + (size_t)B_ * C_ * N_;   // second tuple element, f32

    char* ws = (char*)d_ws;
    // layout (bytes): all offsets 16B-aligned
    bf16*  qh  = (bf16*) (ws + 0);                      //  2 MB [B][N][64]
    bf16*  ql  = (bf16*) (ws + 2097152);                //  2 MB
    bf16*  kh  = (bf16*) (ws + 4194304);                //  2 MB
    bf16*  kl  = (bf16*) (ws + 6291456);                //  2 MB
    bf16*  V   = (bf16*) (ws + 8388608);                // 16 MB [B][C][N]
    bf16*  xTb = (bf16*) (ws + 25165824);               // 16 MB [B][N][C]
    float* WqT = (float*)(ws + 41943040);               // 128 KB [C][D]
    float* WkT = (float*)(ws + 42074112);               // 128 KB [C][D]
    bf16*  Wvb = (bf16*) (ws + 42205184);               // 512 KB [C][C]
    bf16*  attB = (bf16*)(ws + 42729472);               // 128 MB [B][N][N]
    const size_t full_need = 42729472ULL + (size_t)B_ * N_ * N_ * 2;
    bf16* attB_use = (ws_size >= full_need) ? attB : (bf16*)0;

    prep_weights<<<1280, 256, 0, stream>>>(Wq, Wk, Wv, WqT, WkT, Wvb);

    transpose_cast<<<dim3(N_ / 32, C_ / 32, B_), dim3(32, 8), 0, stream>>>(x, xTb);

    proj_qk<<<dim3(N_ / 256, B_, 8), 256, 0, stream>>>(x, WqT, WkT, bq, bk,
                                                       qh, ql, kh, kl);

    proj_v<<<dim3(N_ / 128, C_ / 128, B_), 256, 0, stream>>>(Wvb, xTb, bv, V);

    attn_fused<<<dim3(N_ / 32, B_), 256, 0, stream>>>(qh, ql, kh, kl,
                                                      attF, attB_use);

    if (attB_use) {
        pv_out_fast<<<dim3(N_ / 128, C_ / 128, B_), 256, 0, stream>>>(
            V, attB_use, x, gamma, out);
    } else {
        pv_out<<<dim3(N_ / 128, C_ / 128, B_), 256, 0, stream>>>(
            V, attB_use, attF, x, gamma, out);
    }
}